// Round 2
// baseline (861.093 us; speedup 1.0000x reference)
//
#include <hip/hip_runtime.h>

#define H 128

// deg[i] = 1 (self loop), counter[i] = 0
__global__ __launch_bounds__(256) void k_init(int* __restrict__ deg, int* __restrict__ counter, int n){
  int i = blockIdx.x*blockDim.x + threadIdx.x;
  if (i < n){ deg[i] = 1; counter[i] = 0; }
}

// deg[dst] += 1 per real edge
__global__ __launch_bounds__(256) void k_count(const int* __restrict__ dst, int E, int* __restrict__ deg){
  int i = blockIdx.x*blockDim.x + threadIdx.x;
  int stride = gridDim.x*blockDim.x;
  for (; i < E; i += stride) atomicAdd(&deg[dst[i]], 1);
}

// exclusive scan of deg -> offsets[0..n], plus dinv = rsqrt(deg). Single block, 1024 threads.
__global__ __launch_bounds__(1024) void k_scan(const int* __restrict__ deg, int n,
                                               int* __restrict__ offsets, float* __restrict__ dinv){
  __shared__ int part[1024];
  int t = threadIdx.x;
  int chunk = (n + 1023) / 1024;
  int lo = t * chunk;
  int hi = min(lo + chunk, n);
  int s = 0;
  for (int i = lo; i < hi; i++) s += deg[i];
  part[t] = s;
  __syncthreads();
  for (int off = 1; off < 1024; off <<= 1){
    int v = part[t];
    int add = (t >= off) ? part[t - off] : 0;
    __syncthreads();
    part[t] = v + add;
    __syncthreads();
  }
  int base = (t == 0) ? 0 : part[t-1];
  for (int i = lo; i < hi; i++){
    offsets[i] = base;
    int d = deg[i];
    base += d;
    dinv[i] = rsqrtf((float)d);  // deg >= 1 always (self loop)
  }
  if (t == 1023) offsets[n] = part[1023];
}

// counting-sort edges (incl. self loops) into dst-grouped CSR
__global__ __launch_bounds__(256) void k_fill(const int* __restrict__ src, const int* __restrict__ dst,
            int E, int n,
            const int* __restrict__ offsets, int* __restrict__ counter,
            int* __restrict__ csr_src){
  int i = blockIdx.x*blockDim.x + threadIdx.x;
  int total = E + n;
  int stride = gridDim.x*blockDim.x;
  for (; i < total; i += stride){
    int s, d;
    if (i < E){ s = src[i]; d = dst[i]; } else { s = i - E; d = s; }
    int p = offsets[d] + atomicAdd(&counter[d], 1);
    csr_src[p] = s;
  }
}

// h = pos @ W1   ([N,3] x [3,128]); bias added after aggregation
__global__ __launch_bounds__(128) void k_dense3(const float* __restrict__ pos, const float* __restrict__ W1,
                                                float* __restrict__ h, int n){
  int node = blockIdx.x;
  if (node >= n) return;
  int f = threadIdx.x;
  float p0 = pos[node*3+0], p1 = pos[node*3+1], p2 = pos[node*3+2];
  float w0 = W1[0*H+f],     w1 = W1[1*H+f],     w2 = W1[2*H+f];
  h[node*H+f] = p0*w0 + p1*w1 + p2*w2;
}

// x[node] = relu( sum_e h[src_e]*norm_e + bias )    one block per node, thread = feature
__global__ __launch_bounds__(128) void k_aggregate(const float* __restrict__ h, const int* __restrict__ offsets,
                 const int* __restrict__ csr_src, const float* __restrict__ dinv,
                 const float* __restrict__ bias, float* __restrict__ x, int n){
  int node = blockIdx.x;
  if (node >= n) return;
  int f = threadIdx.x;
  int lo = offsets[node], hi = offsets[node+1];
  float dn = dinv[node];
  float acc = 0.f;
  for (int e = lo; e < hi; e++){
    int s = csr_src[e];           // uniform across block -> broadcast load
    float nm = dinv[s] * dn;      // norm computed on the fly
    acc += h[s*H+f] * nm;         // coalesced 512B row gather
  }
  acc += bias[f];
  x[node*H+f] = fmaxf(acc, 0.f);
}

// hout = x @ W   ([N,128] x [128,128]), fp32, 4x4 register tile / thread,
// 32 rows per block; W staged in LDS in two K-halves (48KB LDS total)
__global__ __launch_bounds__(256) void k_dense128(const float* __restrict__ x, const float* __restrict__ W,
                                                  float* __restrict__ hout, int n){
  __shared__ float ws[64*H];   // 32KB: half of W
  __shared__ float xs[32*H];   // 16KB: 32 input rows
  int tid = threadIdx.x;
  int row0 = blockIdx.x * 32;
  for (int i = tid; i < 32*H; i += 256){
    int r = i >> 7, c = i & 127;
    int gr = row0 + r;
    xs[i] = (gr < n) ? x[(size_t)gr*H + c] : 0.f;
  }
  int fb = (tid & 31) * 4;   // 4 consecutive output features
  int rb = (tid >> 5) * 4;   // 4 rows
  float acc[4][4] = {};
  for (int half = 0; half < 2; half++){
    __syncthreads();   // xs ready / previous half's compute done
    for (int i = tid; i < 64*H; i += 256) ws[i] = W[half*64*H + i];
    __syncthreads();
    for (int k = 0; k < 64; k++){
      float w0 = ws[k*H+fb+0], w1 = ws[k*H+fb+1], w2 = ws[k*H+fb+2], w3 = ws[k*H+fb+3];
      #pragma unroll
      for (int j = 0; j < 4; j++){
        float xv = xs[(rb+j)*H + half*64 + k];
        acc[j][0] += xv*w0; acc[j][1] += xv*w1; acc[j][2] += xv*w2; acc[j][3] += xv*w3;
      }
    }
  }
  for (int j = 0; j < 4; j++){
    int gr = row0 + rb + j;
    if (gr < n){
      *(float4*)&hout[(size_t)gr*H + fb] = make_float4(acc[j][0], acc[j][1], acc[j][2], acc[j][3]);
    }
  }
}

// mean-pool per graph (batch is sorted): block per graph, binary-search bounds
__global__ __launch_bounds__(128) void k_pool(const float* __restrict__ x, const int* __restrict__ batch,
                                              int n, float* __restrict__ gmean){
  int g = blockIdx.x;
  __shared__ int sh[2];
  if (threadIdx.x == 0){
    int lo = 0, hi = n;
    while (lo < hi){ int m = (lo + hi) >> 1; if (batch[m] < g) lo = m + 1; else hi = m; }
    sh[0] = lo;
    lo = 0; hi = n;
    while (lo < hi){ int m = (lo + hi) >> 1; if (batch[m] < g + 1) lo = m + 1; else hi = m; }
    sh[1] = lo;
  }
  __syncthreads();
  int lo = sh[0], hi = sh[1];
  int f = threadIdx.x;
  float acc = 0.f;
  for (int i = lo; i < hi; i++) acc += x[(size_t)i*H + f];
  float cnt = (float)(hi - lo);
  gmean[g*H + f] = acc / fmaxf(cnt, 1.f);
}

// MLP head: relu(g @ Wl1 + bl1) @ Wl2 + bl2   -> fp32 out [G,10]
__global__ __launch_bounds__(64) void k_head(const float* __restrict__ gmean,
            const float* __restrict__ Wl1, const float* __restrict__ bl1,
            const float* __restrict__ Wl2, const float* __restrict__ bl2,
            float* __restrict__ out){
  int g = blockIdx.x;
  int t = threadIdx.x;  // 64
  __shared__ float gs[H];
  __shared__ float h1[64];
  gs[t] = gmean[g*H + t];
  gs[64 + t] = gmean[g*H + 64 + t];
  __syncthreads();
  float acc = bl1[t];
  for (int k = 0; k < H; k++) acc += gs[k] * Wl1[k*64 + t];
  h1[t] = fmaxf(acc, 0.f);
  __syncthreads();
  if (t < 10){
    float o = bl2[t];
    for (int j = 0; j < 64; j++) o += h1[j] * Wl2[j*10 + t];
    out[g*10 + t] = o;
  }
}

extern "C" void kernel_launch(void* const* d_in, const int* in_sizes, int n_in,
                              void* d_out, int out_size, void* d_ws, size_t ws_size,
                              hipStream_t stream){
  const float* pos = (const float*)d_in[0];
  const int*  ei   = (const int*)d_in[1];
  const int*  batch= (const int*)d_in[2];
  const float* W1 = (const float*)d_in[3];
  const float* b1 = (const float*)d_in[4];
  const float* W2 = (const float*)d_in[5];
  const float* b2 = (const float*)d_in[6];
  const float* W3 = (const float*)d_in[7];
  const float* b3 = (const float*)d_in[8];
  const float* Wl1 = (const float*)d_in[9];
  const float* bl1 = (const float*)d_in[10];
  const float* Wl2 = (const float*)d_in[11];
  const float* bl2 = (const float*)d_in[12];
  float* out = (float*)d_out;

  int N = in_sizes[0] / 3;     // 50000
  int E = in_sizes[1] / 2;     // 800000
  int G = out_size / 10;       // 64

  // workspace carve (~56 MB total)
  char* p = (char*)d_ws;
  auto carve = [&](size_t bytes)->char* { char* q = p; p += (bytes + 255) & ~(size_t)255; return q; };
  int*   deg      = (int*)  carve(sizeof(int)   * (size_t)N);
  int*   offsets  = (int*)  carve(sizeof(int)   * (size_t)(N+1));
  int*   counter  = (int*)  carve(sizeof(int)   * (size_t)N);
  float* dinv     = (float*)carve(sizeof(float) * (size_t)N);
  int*   csr_src  = (int*)  carve(sizeof(int)   * (size_t)(E+N));
  float* hbuf     = (float*)carve(sizeof(float) * (size_t)N * H);
  float* xbuf     = (float*)carve(sizeof(float) * (size_t)N * H);
  float* gmean    = (float*)carve(sizeof(float) * (size_t)G * H);

  const int* src = ei;
  const int* dst = ei + E;

  hipLaunchKernelGGL(k_init,  dim3((N+255)/256),   dim3(256),  0, stream, deg, counter, N);
  hipLaunchKernelGGL(k_count, dim3((E+255)/256),   dim3(256),  0, stream, dst, E, deg);
  hipLaunchKernelGGL(k_scan,  dim3(1),             dim3(1024), 0, stream, deg, N, offsets, dinv);
  hipLaunchKernelGGL(k_fill,  dim3((E+N+255)/256), dim3(256),  0, stream, src, dst, E, N, offsets, counter, csr_src);

  hipLaunchKernelGGL(k_dense3,    dim3(N), dim3(128), 0, stream, pos, W1, hbuf, N);
  hipLaunchKernelGGL(k_aggregate, dim3(N), dim3(128), 0, stream, hbuf, offsets, csr_src, dinv, b1, xbuf, N);

  hipLaunchKernelGGL(k_dense128,  dim3((N+31)/32), dim3(256), 0, stream, xbuf, W2, hbuf, N);
  hipLaunchKernelGGL(k_aggregate, dim3(N), dim3(128), 0, stream, hbuf, offsets, csr_src, dinv, b2, xbuf, N);

  hipLaunchKernelGGL(k_dense128,  dim3((N+31)/32), dim3(256), 0, stream, xbuf, W3, hbuf, N);
  hipLaunchKernelGGL(k_aggregate, dim3(N), dim3(128), 0, stream, hbuf, offsets, csr_src, dinv, b3, xbuf, N);

  hipLaunchKernelGGL(k_pool, dim3(G), dim3(128), 0, stream, xbuf, batch, N, gmean);
  hipLaunchKernelGGL(k_head, dim3(G), dim3(64),  0, stream, gmean, Wl1, bl1, Wl2, bl2, out);
}

// Round 3
// 582.529 us; speedup vs baseline: 1.4782x; 1.4782x over previous
//
#include <hip/hip_runtime.h>

#define H 128

// deg[i] = 1 (self loop), counter[i] = 0
__global__ __launch_bounds__(256) void k_init(int* __restrict__ deg, int* __restrict__ counter, int n){
  int i = blockIdx.x*blockDim.x + threadIdx.x;
  if (i < n){ deg[i] = 1; counter[i] = 0; }
}

// deg[dst] += 1 per real edge
__global__ __launch_bounds__(256) void k_count(const int* __restrict__ dst, int E, int* __restrict__ deg){
  int i = blockIdx.x*blockDim.x + threadIdx.x;
  int stride = gridDim.x*blockDim.x;
  for (; i < E; i += stride) atomicAdd(&deg[dst[i]], 1);
}

// exclusive scan of deg -> offsets[0..n], plus dinv = rsqrt(deg). Single block, 1024 threads.
__global__ __launch_bounds__(1024) void k_scan(const int* __restrict__ deg, int n,
                                               int* __restrict__ offsets, float* __restrict__ dinv){
  __shared__ int part[1024];
  int t = threadIdx.x;
  int chunk = (n + 1023) / 1024;
  int lo = t * chunk;
  int hi = min(lo + chunk, n);
  int s = 0;
  for (int i = lo; i < hi; i++) s += deg[i];
  part[t] = s;
  __syncthreads();
  for (int off = 1; off < 1024; off <<= 1){
    int v = part[t];
    int add = (t >= off) ? part[t - off] : 0;
    __syncthreads();
    part[t] = v + add;
    __syncthreads();
  }
  int base = (t == 0) ? 0 : part[t-1];
  for (int i = lo; i < hi; i++){
    offsets[i] = base;
    int d = deg[i];
    base += d;
    dinv[i] = rsqrtf((float)d);  // deg >= 1 always (self loop)
  }
  if (t == 1023) offsets[n] = part[1023];
}

// counting-sort edges (incl. self loops) into dst-grouped CSR
__global__ __launch_bounds__(256) void k_fill(const int* __restrict__ src, const int* __restrict__ dst,
            int E, int n,
            const int* __restrict__ offsets, int* __restrict__ counter,
            int* __restrict__ csr_src){
  int i = blockIdx.x*blockDim.x + threadIdx.x;
  int total = E + n;
  int stride = gridDim.x*blockDim.x;
  for (; i < total; i += stride){
    int s, d;
    if (i < E){ s = src[i]; d = dst[i]; } else { s = i - E; d = s; }
    int p = offsets[d] + atomicAdd(&counter[d], 1);
    csr_src[p] = s;
  }
}

// h = pos @ W1   ([N,3] x [3,128]); bias added after aggregation
__global__ __launch_bounds__(128) void k_dense3(const float* __restrict__ pos, const float* __restrict__ W1,
                                                float* __restrict__ h, int n){
  int node = blockIdx.x;
  if (node >= n) return;
  int f = threadIdx.x;
  float p0 = pos[node*3+0], p1 = pos[node*3+1], p2 = pos[node*3+2];
  float w0 = W1[0*H+f],     w1 = W1[1*H+f],     w2 = W1[2*H+f];
  h[node*H+f] = p0*w0 + p1*w1 + p2*w2;
}

// x[node] = relu( sum_e h[src_e]*norm_e + bias )
// 8 nodes per 256-thread block; 32 lanes per node, float4 per lane (16B/lane)
__global__ __launch_bounds__(256) void k_aggregate(const float* __restrict__ h, const int* __restrict__ offsets,
                 const int* __restrict__ csr_src, const float* __restrict__ dinv,
                 const float* __restrict__ bias, float* __restrict__ x, int n){
  int node = blockIdx.x*8 + (threadIdx.x >> 5);
  if (node >= n) return;
  int f4 = (threadIdx.x & 31) * 4;
  int lo = offsets[node], hi = offsets[node+1];
  float dn = dinv[node];
  float ax=0.f, ay=0.f, az=0.f, aw=0.f;
  for (int e = lo; e < hi; e++){
    int s = csr_src[e];           // uniform across 32-lane group -> broadcast
    float nm = dinv[s] * dn;
    float4 v = *(const float4*)&h[(size_t)s*H + f4];  // 512B row gather
    ax += v.x*nm; ay += v.y*nm; az += v.z*nm; aw += v.w*nm;
  }
  float4 b = *(const float4*)&bias[f4];
  float4 o = make_float4(fmaxf(ax+b.x,0.f), fmaxf(ay+b.y,0.f), fmaxf(az+b.z,0.f), fmaxf(aw+b.w,0.f));
  *(float4*)&x[(size_t)node*H + f4] = o;
}

// hout = x @ W   ([N,128] x [128,128]), fp32, 4x4 register tile / thread,
// 32 rows per block; W staged in LDS in two K-halves (48KB LDS total)
__global__ __launch_bounds__(256) void k_dense128(const float* __restrict__ x, const float* __restrict__ W,
                                                  float* __restrict__ hout, int n){
  __shared__ float ws[64*H];   // 32KB: half of W
  __shared__ float xs[32*H];   // 16KB: 32 input rows
  int tid = threadIdx.x;
  int row0 = blockIdx.x * 32;
  for (int i = tid; i < 32*H; i += 256){
    int r = i >> 7, c = i & 127;
    int gr = row0 + r;
    xs[i] = (gr < n) ? x[(size_t)gr*H + c] : 0.f;
  }
  int fb = (tid & 31) * 4;   // 4 consecutive output features
  int rb = (tid >> 5) * 4;   // 4 rows
  float acc[4][4] = {};
  for (int half = 0; half < 2; half++){
    __syncthreads();   // xs ready / previous half's compute done
    for (int i = tid; i < 64*H; i += 256) ws[i] = W[half*64*H + i];
    __syncthreads();
    for (int k = 0; k < 64; k++){
      float w0 = ws[k*H+fb+0], w1 = ws[k*H+fb+1], w2 = ws[k*H+fb+2], w3 = ws[k*H+fb+3];
      #pragma unroll
      for (int j = 0; j < 4; j++){
        float xv = xs[(rb+j)*H + half*64 + k];
        acc[j][0] += xv*w0; acc[j][1] += xv*w1; acc[j][2] += xv*w2; acc[j][3] += xv*w3;
      }
    }
  }
  for (int j = 0; j < 4; j++){
    int gr = row0 + rb + j;
    if (gr < n){
      *(float4*)&hout[(size_t)gr*H + fb] = make_float4(acc[j][0], acc[j][1], acc[j][2], acc[j][3]);
    }
  }
}

// graph boundaries: gb[g] = first node index with batch >= g, g in [0, G]
__global__ __launch_bounds__(64) void k_bounds(const int* __restrict__ batch, int n, int G,
                                               int* __restrict__ gb){
  int g = blockIdx.x*blockDim.x + threadIdx.x;
  if (g > G) return;
  int lo = 0, hi = n;
  while (lo < hi){ int m = (lo + hi) >> 1; if (batch[m] < g) lo = m + 1; else hi = m; }
  gb[g] = lo;
}

// partial pooled sums: grid (G, S); block sums a slice of graph g's rows, one atomic per feature
__global__ __launch_bounds__(128) void k_pool_partial(const float* __restrict__ x, const int* __restrict__ gb,
                                                      int S, float* __restrict__ gsum){
  int g = blockIdx.x, s = blockIdx.y;
  int lo = gb[g], hi = gb[g+1];
  int cnt = hi - lo;
  int a = lo + (int)(((long long)cnt * s) / S);
  int b = lo + (int)(((long long)cnt * (s+1)) / S);
  int f = threadIdx.x;
  float acc = 0.f;
  for (int i = a; i < b; i++) acc += x[(size_t)i*H + f];
  if (b > a) atomicAdd(&gsum[g*H + f], acc);
}

// MLP head: relu((gsum/cnt) @ Wl1 + bl1) @ Wl2 + bl2   -> fp32 out [G,10]
__global__ __launch_bounds__(64) void k_head(const float* __restrict__ gsum, const int* __restrict__ gb,
            const float* __restrict__ Wl1, const float* __restrict__ bl1,
            const float* __restrict__ Wl2, const float* __restrict__ bl2,
            float* __restrict__ out){
  int g = blockIdx.x;
  int t = threadIdx.x;  // 64
  __shared__ float gs[H];
  __shared__ float h1[64];
  float inv = 1.f / fmaxf((float)(gb[g+1] - gb[g]), 1.f);
  gs[t]      = gsum[g*H + t]      * inv;
  gs[64 + t] = gsum[g*H + 64 + t] * inv;
  __syncthreads();
  float acc = bl1[t];
  for (int k = 0; k < H; k++) acc += gs[k] * Wl1[k*64 + t];
  h1[t] = fmaxf(acc, 0.f);
  __syncthreads();
  if (t < 10){
    float o = bl2[t];
    for (int j = 0; j < 64; j++) o += h1[j] * Wl2[j*10 + t];
    out[g*10 + t] = o;
  }
}

extern "C" void kernel_launch(void* const* d_in, const int* in_sizes, int n_in,
                              void* d_out, int out_size, void* d_ws, size_t ws_size,
                              hipStream_t stream){
  const float* pos = (const float*)d_in[0];
  const int*  ei   = (const int*)d_in[1];
  const int*  batch= (const int*)d_in[2];
  const float* W1 = (const float*)d_in[3];
  const float* b1 = (const float*)d_in[4];
  const float* W2 = (const float*)d_in[5];
  const float* b2 = (const float*)d_in[6];
  const float* W3 = (const float*)d_in[7];
  const float* b3 = (const float*)d_in[8];
  const float* Wl1 = (const float*)d_in[9];
  const float* bl1 = (const float*)d_in[10];
  const float* Wl2 = (const float*)d_in[11];
  const float* bl2 = (const float*)d_in[12];
  float* out = (float*)d_out;

  int N = in_sizes[0] / 3;     // 50000
  int E = in_sizes[1] / 2;     // 800000
  int G = out_size / 10;       // 64
  const int S = 40;            // pooling splits per graph

  // workspace carve (~56 MB total)
  char* p = (char*)d_ws;
  auto carve = [&](size_t bytes)->char* { char* q = p; p += (bytes + 255) & ~(size_t)255; return q; };
  int*   deg      = (int*)  carve(sizeof(int)   * (size_t)N);
  int*   offsets  = (int*)  carve(sizeof(int)   * (size_t)(N+1));
  int*   counter  = (int*)  carve(sizeof(int)   * (size_t)N);
  float* dinv     = (float*)carve(sizeof(float) * (size_t)N);
  int*   csr_src  = (int*)  carve(sizeof(int)   * (size_t)(E+N));
  float* hbuf     = (float*)carve(sizeof(float) * (size_t)N * H);
  float* xbuf     = (float*)carve(sizeof(float) * (size_t)N * H);
  int*   gb       = (int*)  carve(sizeof(int)   * (size_t)(G+1));
  float* gsum     = (float*)carve(sizeof(float) * (size_t)G * H);

  const int* src = ei;
  const int* dst = ei + E;

  hipMemsetAsync(gsum, 0, sizeof(float)*(size_t)G*H, stream);
  hipLaunchKernelGGL(k_bounds, dim3((G+64)/64), dim3(64), 0, stream, batch, N, G, gb);

  hipLaunchKernelGGL(k_init,  dim3((N+255)/256),   dim3(256),  0, stream, deg, counter, N);
  hipLaunchKernelGGL(k_count, dim3((E+255)/256),   dim3(256),  0, stream, dst, E, deg);
  hipLaunchKernelGGL(k_scan,  dim3(1),             dim3(1024), 0, stream, deg, N, offsets, dinv);
  hipLaunchKernelGGL(k_fill,  dim3((E+N+255)/256), dim3(256),  0, stream, src, dst, E, N, offsets, counter, csr_src);

  hipLaunchKernelGGL(k_dense3,    dim3(N),         dim3(128), 0, stream, pos, W1, hbuf, N);
  hipLaunchKernelGGL(k_aggregate, dim3((N+7)/8),   dim3(256), 0, stream, hbuf, offsets, csr_src, dinv, b1, xbuf, N);

  hipLaunchKernelGGL(k_dense128,  dim3((N+31)/32), dim3(256), 0, stream, xbuf, W2, hbuf, N);
  hipLaunchKernelGGL(k_aggregate, dim3((N+7)/8),   dim3(256), 0, stream, hbuf, offsets, csr_src, dinv, b2, xbuf, N);

  hipLaunchKernelGGL(k_dense128,  dim3((N+31)/32), dim3(256), 0, stream, xbuf, W3, hbuf, N);
  hipLaunchKernelGGL(k_aggregate, dim3((N+7)/8),   dim3(256), 0, stream, hbuf, offsets, csr_src, dinv, b3, xbuf, N);

  hipLaunchKernelGGL(k_pool_partial, dim3(G, S), dim3(128), 0, stream, xbuf, gb, S, gsum);
  hipLaunchKernelGGL(k_head,         dim3(G),    dim3(64),  0, stream, gsum, gb, Wl1, bl1, Wl2, bl2, out);
}

// Round 4
// 504.199 us; speedup vs baseline: 1.7078x; 1.1554x over previous
//
#include <hip/hip_runtime.h>

#define H 128

// deg[i] = 1 (self loop), counter[i] = 0
__global__ __launch_bounds__(256) void k_init(int* __restrict__ deg, int* __restrict__ counter, int n){
  int i = blockIdx.x*blockDim.x + threadIdx.x;
  if (i < n){ deg[i] = 1; counter[i] = 0; }
}

// deg[dst] += 1 per real edge
__global__ __launch_bounds__(256) void k_count(const int* __restrict__ dst, int E, int* __restrict__ deg){
  int i = blockIdx.x*blockDim.x + threadIdx.x;
  int stride = gridDim.x*blockDim.x;
  for (; i < E; i += stride) atomicAdd(&deg[dst[i]], 1);
}

// ---- multi-block exclusive scan of deg -> offsets, plus dinv ----
// phase 1: block-local scan (1024 items/block), block totals to bsum
__global__ __launch_bounds__(256) void k_scan1(const int* __restrict__ deg, int n,
      int* __restrict__ offsets, int* __restrict__ bsum, float* __restrict__ dinv){
  __shared__ int sh[256];
  int b = blockIdx.x, t = threadIdx.x;
  int base = b*1024 + t*4;
  int d0=0,d1=0,d2=0,d3=0;
  if (base+3 < n){ int4 v = *(const int4*)&deg[base]; d0=v.x; d1=v.y; d2=v.z; d3=v.w; }
  else {
    if (base+0 < n) d0 = deg[base+0];
    if (base+1 < n) d1 = deg[base+1];
    if (base+2 < n) d2 = deg[base+2];
    if (base+3 < n) d3 = deg[base+3];
  }
  sh[t] = d0+d1+d2+d3;
  __syncthreads();
  for (int off=1; off<256; off<<=1){
    int v = sh[t];
    int add = (t>=off)? sh[t-off] : 0;
    __syncthreads();
    sh[t] = v+add;
    __syncthreads();
  }
  int o0 = (t==0)?0:sh[t-1];
  int o1 = o0+d0, o2 = o1+d1, o3 = o2+d2;
  if (base+0 < n){ offsets[base+0]=o0; dinv[base+0]=rsqrtf((float)d0); }
  if (base+1 < n){ offsets[base+1]=o1; dinv[base+1]=rsqrtf((float)d1); }
  if (base+2 < n){ offsets[base+2]=o2; dinv[base+2]=rsqrtf((float)d2); }
  if (base+3 < n){ offsets[base+3]=o3; dinv[base+3]=rsqrtf((float)d3); }
  if (t==255) bsum[b] = sh[255];
}

// phase 2: scan the block totals (B <= 256), convert to exclusive, write grand total
__global__ __launch_bounds__(256) void k_scan2(int* __restrict__ bsum, int B, int n, int* __restrict__ offsets){
  __shared__ int sh[256];
  int t = threadIdx.x;
  sh[t] = (t<B)? bsum[t] : 0;
  __syncthreads();
  for (int off=1; off<256; off<<=1){
    int v = sh[t];
    int add = (t>=off)? sh[t-off] : 0;
    __syncthreads();
    sh[t] = v+add;
    __syncthreads();
  }
  if (t<B) bsum[t] = (t==0)?0:sh[t-1];
  if (t==255) offsets[n] = sh[255];
}

// phase 3: add block prefix
__global__ __launch_bounds__(256) void k_scan3(int* __restrict__ offsets, int n, const int* __restrict__ bsum){
  int b = blockIdx.x, t = threadIdx.x;
  int add = bsum[b];
  int base = b*1024 + t*4;
  if (base+3 < n){
    int4 v = *(int4*)&offsets[base];
    v.x+=add; v.y+=add; v.z+=add; v.w+=add;
    *(int4*)&offsets[base] = v;
  } else {
    #pragma unroll
    for (int k=0;k<4;k++){ int i=base+k; if (i<n) offsets[i]+=add; }
  }
}

// counting-sort edges (incl. self loops) into dst-grouped CSR, norm precomputed
__global__ __launch_bounds__(256) void k_fill(const int* __restrict__ src, const int* __restrict__ dst,
            int E, int n,
            const int* __restrict__ offsets, int* __restrict__ counter, const float* __restrict__ dinv,
            int* __restrict__ csr_src, float* __restrict__ csr_norm){
  int i = blockIdx.x*blockDim.x + threadIdx.x;
  int total = E + n;
  int stride = gridDim.x*blockDim.x;
  for (; i < total; i += stride){
    int s, d;
    if (i < E){ s = src[i]; d = dst[i]; } else { s = i - E; d = s; }
    int p = offsets[d] + atomicAdd(&counter[d], 1);
    csr_src[p] = s;
    csr_norm[p] = dinv[s] * dinv[d];
  }
}

// h = pos @ W1   ([N,3] x [3,128]); bias added after aggregation
__global__ __launch_bounds__(128) void k_dense3(const float* __restrict__ pos, const float* __restrict__ W1,
                                                float* __restrict__ h, int n){
  int node = blockIdx.x;
  if (node >= n) return;
  int f = threadIdx.x;
  float p0 = pos[node*3+0], p1 = pos[node*3+1], p2 = pos[node*3+2];
  float w0 = W1[0*H+f],     w1 = W1[1*H+f],     w2 = W1[2*H+f];
  h[node*H+f] = p0*w0 + p1*w1 + p2*w2;
}

// x[node] = relu( sum_e h[src_e]*norm_e + bias )
// 8 nodes per 256-thread block; 32 lanes per node, float4 per lane; unroll-by-4
__global__ __launch_bounds__(256) void k_aggregate(const float* __restrict__ h, const int* __restrict__ offsets,
                 const int* __restrict__ csr_src, const float* __restrict__ csr_norm,
                 const float* __restrict__ bias, float* __restrict__ x, int n){
  int node = blockIdx.x*8 + (threadIdx.x >> 5);
  if (node >= n) return;
  int f4 = (threadIdx.x & 31) * 4;
  int lo = offsets[node], hi = offsets[node+1];
  float ax=0.f, ay=0.f, az=0.f, aw=0.f;
  int e = lo;
  for (; e + 4 <= hi; e += 4){
    int s0=csr_src[e], s1=csr_src[e+1], s2=csr_src[e+2], s3=csr_src[e+3];
    float n0=csr_norm[e], n1=csr_norm[e+1], n2=csr_norm[e+2], n3=csr_norm[e+3];
    float4 v0 = *(const float4*)&h[(size_t)s0*H + f4];   // 4 independent row gathers
    float4 v1 = *(const float4*)&h[(size_t)s1*H + f4];
    float4 v2 = *(const float4*)&h[(size_t)s2*H + f4];
    float4 v3 = *(const float4*)&h[(size_t)s3*H + f4];
    ax += v0.x*n0 + v1.x*n1 + v2.x*n2 + v3.x*n3;
    ay += v0.y*n0 + v1.y*n1 + v2.y*n2 + v3.y*n3;
    az += v0.z*n0 + v1.z*n1 + v2.z*n2 + v3.z*n3;
    aw += v0.w*n0 + v1.w*n1 + v2.w*n2 + v3.w*n3;
  }
  for (; e < hi; e++){
    int s = csr_src[e];
    float nm = csr_norm[e];
    float4 v = *(const float4*)&h[(size_t)s*H + f4];
    ax += v.x*nm; ay += v.y*nm; az += v.z*nm; aw += v.w*nm;
  }
  float4 b = *(const float4*)&bias[f4];
  float4 o = make_float4(fmaxf(ax+b.x,0.f), fmaxf(ay+b.y,0.f), fmaxf(az+b.z,0.f), fmaxf(aw+b.w,0.f));
  *(float4*)&x[(size_t)node*H + f4] = o;
}

// hout = x @ W   ([N,128] x [128,128]), fp32, 4x4 register tile / thread,
// 32 rows per block; W staged in LDS in two K-halves (48KB LDS total)
__global__ __launch_bounds__(256) void k_dense128(const float* __restrict__ x, const float* __restrict__ W,
                                                  float* __restrict__ hout, int n){
  __shared__ float ws[64*H];   // 32KB: half of W
  __shared__ float xs[32*H];   // 16KB: 32 input rows
  int tid = threadIdx.x;
  int row0 = blockIdx.x * 32;
  for (int i = tid; i < 32*H; i += 256){
    int r = i >> 7, c = i & 127;
    int gr = row0 + r;
    xs[i] = (gr < n) ? x[(size_t)gr*H + c] : 0.f;
  }
  int fb = (tid & 31) * 4;   // 4 consecutive output features
  int rb = (tid >> 5) * 4;   // 4 rows
  float acc[4][4] = {};
  for (int half = 0; half < 2; half++){
    __syncthreads();
    for (int i = tid; i < 64*H; i += 256) ws[i] = W[half*64*H + i];
    __syncthreads();
    for (int k = 0; k < 64; k++){
      float w0 = ws[k*H+fb+0], w1 = ws[k*H+fb+1], w2 = ws[k*H+fb+2], w3 = ws[k*H+fb+3];
      #pragma unroll
      for (int j = 0; j < 4; j++){
        float xv = xs[(rb+j)*H + half*64 + k];
        acc[j][0] += xv*w0; acc[j][1] += xv*w1; acc[j][2] += xv*w2; acc[j][3] += xv*w3;
      }
    }
  }
  for (int j = 0; j < 4; j++){
    int gr = row0 + rb + j;
    if (gr < n){
      *(float4*)&hout[(size_t)gr*H + fb] = make_float4(acc[j][0], acc[j][1], acc[j][2], acc[j][3]);
    }
  }
}

// graph boundaries: gb[g] = first node index with batch >= g, g in [0, G]
__global__ __launch_bounds__(64) void k_bounds(const int* __restrict__ batch, int n, int G,
                                               int* __restrict__ gb){
  int g = blockIdx.x*blockDim.x + threadIdx.x;
  if (g > G) return;
  int lo = 0, hi = n;
  while (lo < hi){ int m = (lo + hi) >> 1; if (batch[m] < g) lo = m + 1; else hi = m; }
  gb[g] = lo;
}

// partial pooled sums: grid (G, S); block sums a slice of graph g's rows, one atomic per feature
__global__ __launch_bounds__(128) void k_pool_partial(const float* __restrict__ x, const int* __restrict__ gb,
                                                      int S, float* __restrict__ gsum){
  int g = blockIdx.x, s = blockIdx.y;
  int lo = gb[g], hi = gb[g+1];
  int cnt = hi - lo;
  int a = lo + (int)(((long long)cnt * s) / S);
  int b = lo + (int)(((long long)cnt * (s+1)) / S);
  int f = threadIdx.x;
  float acc = 0.f;
  for (int i = a; i < b; i++) acc += x[(size_t)i*H + f];
  if (b > a) atomicAdd(&gsum[g*H + f], acc);
}

// MLP head: relu((gsum/cnt) @ Wl1 + bl1) @ Wl2 + bl2   -> fp32 out [G,10]
__global__ __launch_bounds__(64) void k_head(const float* __restrict__ gsum, const int* __restrict__ gb,
            const float* __restrict__ Wl1, const float* __restrict__ bl1,
            const float* __restrict__ Wl2, const float* __restrict__ bl2,
            float* __restrict__ out){
  int g = blockIdx.x;
  int t = threadIdx.x;  // 64
  __shared__ float gs[H];
  __shared__ float h1[64];
  float inv = 1.f / fmaxf((float)(gb[g+1] - gb[g]), 1.f);
  gs[t]      = gsum[g*H + t]      * inv;
  gs[64 + t] = gsum[g*H + 64 + t] * inv;
  __syncthreads();
  float acc = bl1[t];
  for (int k = 0; k < H; k++) acc += gs[k] * Wl1[k*64 + t];
  h1[t] = fmaxf(acc, 0.f);
  __syncthreads();
  if (t < 10){
    float o = bl2[t];
    for (int j = 0; j < 64; j++) o += h1[j] * Wl2[j*10 + t];
    out[g*10 + t] = o;
  }
}

extern "C" void kernel_launch(void* const* d_in, const int* in_sizes, int n_in,
                              void* d_out, int out_size, void* d_ws, size_t ws_size,
                              hipStream_t stream){
  const float* pos = (const float*)d_in[0];
  const int*  ei   = (const int*)d_in[1];
  const int*  batch= (const int*)d_in[2];
  const float* W1 = (const float*)d_in[3];
  const float* b1 = (const float*)d_in[4];
  const float* W2 = (const float*)d_in[5];
  const float* b2 = (const float*)d_in[6];
  const float* W3 = (const float*)d_in[7];
  const float* b3 = (const float*)d_in[8];
  const float* Wl1 = (const float*)d_in[9];
  const float* bl1 = (const float*)d_in[10];
  const float* Wl2 = (const float*)d_in[11];
  const float* bl2 = (const float*)d_in[12];
  float* out = (float*)d_out;

  int N = in_sizes[0] / 3;     // 50000
  int E = in_sizes[1] / 2;     // 800000
  int G = out_size / 10;       // 64
  const int S = 40;            // pooling splits per graph
  int B = (N + 1023) / 1024;   // scan blocks (49), must be <= 256

  // workspace carve (~60 MB total)
  char* p = (char*)d_ws;
  auto carve = [&](size_t bytes)->char* { char* q = p; p += (bytes + 255) & ~(size_t)255; return q; };
  int*   deg      = (int*)  carve(sizeof(int)   * (size_t)N);
  int*   offsets  = (int*)  carve(sizeof(int)   * (size_t)(N+1));
  int*   counter  = (int*)  carve(sizeof(int)   * (size_t)N);
  float* dinv     = (float*)carve(sizeof(float) * (size_t)N);
  int*   bsum     = (int*)  carve(sizeof(int)   * 256);
  int*   csr_src  = (int*)  carve(sizeof(int)   * (size_t)(E+N));
  float* csr_norm = (float*)carve(sizeof(float) * (size_t)(E+N));
  float* hbuf     = (float*)carve(sizeof(float) * (size_t)N * H);
  float* xbuf     = (float*)carve(sizeof(float) * (size_t)N * H);
  int*   gb       = (int*)  carve(sizeof(int)   * (size_t)(G+1));
  float* gsum     = (float*)carve(sizeof(float) * (size_t)G * H);

  const int* src = ei;
  const int* dst = ei + E;

  hipMemsetAsync(gsum, 0, sizeof(float)*(size_t)G*H, stream);
  hipLaunchKernelGGL(k_bounds, dim3((G+64)/64), dim3(64), 0, stream, batch, N, G, gb);

  hipLaunchKernelGGL(k_init,  dim3((N+255)/256),   dim3(256),  0, stream, deg, counter, N);
  hipLaunchKernelGGL(k_count, dim3((E+255)/256),   dim3(256),  0, stream, dst, E, deg);
  hipLaunchKernelGGL(k_scan1, dim3(B),             dim3(256),  0, stream, deg, N, offsets, bsum, dinv);
  hipLaunchKernelGGL(k_scan2, dim3(1),             dim3(256),  0, stream, bsum, B, N, offsets);
  hipLaunchKernelGGL(k_scan3, dim3(B),             dim3(256),  0, stream, offsets, N, bsum);
  hipLaunchKernelGGL(k_fill,  dim3((E+N+255)/256), dim3(256),  0, stream, src, dst, E, N, offsets, counter, dinv, csr_src, csr_norm);

  hipLaunchKernelGGL(k_dense3,    dim3(N),         dim3(128), 0, stream, pos, W1, hbuf, N);
  hipLaunchKernelGGL(k_aggregate, dim3((N+7)/8),   dim3(256), 0, stream, hbuf, offsets, csr_src, csr_norm, b1, xbuf, N);

  hipLaunchKernelGGL(k_dense128,  dim3((N+31)/32), dim3(256), 0, stream, xbuf, W2, hbuf, N);
  hipLaunchKernelGGL(k_aggregate, dim3((N+7)/8),   dim3(256), 0, stream, hbuf, offsets, csr_src, csr_norm, b2, xbuf, N);

  hipLaunchKernelGGL(k_dense128,  dim3((N+31)/32), dim3(256), 0, stream, xbuf, W3, hbuf, N);
  hipLaunchKernelGGL(k_aggregate, dim3((N+7)/8),   dim3(256), 0, stream, hbuf, offsets, csr_src, csr_norm, b3, xbuf, N);

  hipLaunchKernelGGL(k_pool_partial, dim3(G, S), dim3(128), 0, stream, xbuf, gb, S, gsum);
  hipLaunchKernelGGL(k_head,         dim3(G),    dim3(64),  0, stream, gsum, gb, Wl1, bl1, Wl2, bl2, out);
}

// Round 5
// 349.591 us; speedup vs baseline: 2.4631x; 1.4423x over previous
//
#include <hip/hip_runtime.h>

#define H 128
typedef unsigned int uint32;
typedef unsigned short ushort16;

static __device__ __forceinline__ ushort16 f2bf(float f){
  uint32 u = __float_as_uint(f);
  uint32 r = (u + 0x7fff + ((u >> 16) & 1)) >> 16;   // RNE bf16 (finite values)
  return (ushort16)r;
}
static __device__ __forceinline__ float bflo(uint32 u){ return __uint_as_float(u << 16); }
static __device__ __forceinline__ float bfhi(uint32 u){ return __uint_as_float(u & 0xffff0000u); }

// deg[i] = 1 (self loop), counter[i] = 0
__global__ __launch_bounds__(256) void k_init(int* __restrict__ deg, int* __restrict__ counter, int n){
  int i = blockIdx.x*blockDim.x + threadIdx.x;
  if (i < n){ deg[i] = 1; counter[i] = 0; }
}

__global__ __launch_bounds__(256) void k_count(const int* __restrict__ dst, int E, int* __restrict__ deg){
  int i = blockIdx.x*blockDim.x + threadIdx.x;
  int stride = gridDim.x*blockDim.x;
  for (; i < E; i += stride) atomicAdd(&deg[dst[i]], 1);
}

// ---- multi-block exclusive scan of deg -> offsets, plus dinv ----
__global__ __launch_bounds__(256) void k_scan1(const int* __restrict__ deg, int n,
      int* __restrict__ offsets, int* __restrict__ bsum, float* __restrict__ dinv){
  __shared__ int sh[256];
  int b = blockIdx.x, t = threadIdx.x;
  int base = b*1024 + t*4;
  int d0=0,d1=0,d2=0,d3=0;
  if (base+3 < n){ int4 v = *(const int4*)&deg[base]; d0=v.x; d1=v.y; d2=v.z; d3=v.w; }
  else {
    if (base+0 < n) d0 = deg[base+0];
    if (base+1 < n) d1 = deg[base+1];
    if (base+2 < n) d2 = deg[base+2];
  }
  sh[t] = d0+d1+d2+d3;
  __syncthreads();
  for (int off=1; off<256; off<<=1){
    int v = sh[t];
    int add = (t>=off)? sh[t-off] : 0;
    __syncthreads();
    sh[t] = v+add;
    __syncthreads();
  }
  int o0 = (t==0)?0:sh[t-1];
  int o1 = o0+d0, o2 = o1+d1, o3 = o2+d2;
  if (base+0 < n){ offsets[base+0]=o0; dinv[base+0]=rsqrtf((float)d0); }
  if (base+1 < n){ offsets[base+1]=o1; dinv[base+1]=rsqrtf((float)d1); }
  if (base+2 < n){ offsets[base+2]=o2; dinv[base+2]=rsqrtf((float)d2); }
  if (base+3 < n){ offsets[base+3]=o3; dinv[base+3]=rsqrtf((float)d3); }
  if (t==255) bsum[b] = sh[255];
}

__global__ __launch_bounds__(256) void k_scan2(int* __restrict__ bsum, int B, int n, int* __restrict__ offsets){
  __shared__ int sh[256];
  int t = threadIdx.x;
  sh[t] = (t<B)? bsum[t] : 0;
  __syncthreads();
  for (int off=1; off<256; off<<=1){
    int v = sh[t];
    int add = (t>=off)? sh[t-off] : 0;
    __syncthreads();
    sh[t] = v+add;
    __syncthreads();
  }
  if (t<B) bsum[t] = (t==0)?0:sh[t-1];
  if (t==255) offsets[n] = sh[255];
}

__global__ __launch_bounds__(256) void k_scan3(int* __restrict__ offsets, int n, const int* __restrict__ bsum){
  int b = blockIdx.x, t = threadIdx.x;
  int add = bsum[b];
  int base = b*1024 + t*4;
  if (base+3 < n){
    int4 v = *(int4*)&offsets[base];
    v.x+=add; v.y+=add; v.z+=add; v.w+=add;
    *(int4*)&offsets[base] = v;
  } else {
    #pragma unroll
    for (int k=0;k<4;k++){ int i=base+k; if (i<n) offsets[i]+=add; }
  }
}

// counting-sort edges (incl. self loops) into dst-grouped CSR (indices only)
__global__ __launch_bounds__(256) void k_fill(const int* __restrict__ src, const int* __restrict__ dst,
            int E, int n,
            const int* __restrict__ offsets, int* __restrict__ counter,
            int* __restrict__ csr_src){
  int i = blockIdx.x*blockDim.x + threadIdx.x;
  int total = E + n;
  int stride = gridDim.x*blockDim.x;
  for (; i < total; i += stride){
    int s, d;
    if (i < E){ s = src[i]; d = dst[i]; } else { s = i - E; d = s; }
    int p = offsets[d] + atomicAdd(&counter[d], 1);
    csr_src[p] = s;
  }
}

// y0[i] = dinv[i] * pos[i]  (padded float4)
__global__ __launch_bounds__(256) void k_prescale(const float* __restrict__ pos, const float* __restrict__ dinv,
                                                  float4* __restrict__ y0, int n){
  int i = blockIdx.x*256 + threadIdx.x;
  if (i < n){
    float d = dinv[i];
    y0[i] = make_float4(pos[3*i]*d, pos[3*i+1]*d, pos[3*i+2]*d, 0.f);
  }
}

// a1[d] = dinv[d] * sum_src y0[src]   (3-wide gather: 16B/edge)
__global__ __launch_bounds__(256) void k_agg3(const float4* __restrict__ y0, const int* __restrict__ offsets,
      const int* __restrict__ csr_src, const float* __restrict__ dinv, float4* __restrict__ a1, int n){
  int node = blockIdx.x*256 + threadIdx.x;
  if (node >= n) return;
  int lo = offsets[node], hi = offsets[node+1];
  float x=0.f, y=0.f, z=0.f;
  int e = lo;
  for (; e+2 <= hi; e += 2){
    int s0 = csr_src[e], s1 = csr_src[e+1];
    float4 v0 = y0[s0], v1 = y0[s1];
    x += v0.x + v1.x; y += v0.y + v1.y; z += v0.z + v1.z;
  }
  if (e < hi){ float4 v = y0[csr_src[e]]; x += v.x; y += v.y; z += v.z; }
  float dn = dinv[node];
  a1[node] = make_float4(x*dn, y*dn, z*dn, 0.f);
}

// y1[node,f] = bf16( dinv[node] * relu(a1[node] . W1[:,f] + b1[f]) )
__global__ __launch_bounds__(128) void k_dense1(const float4* __restrict__ a1, const float* __restrict__ W1,
      const float* __restrict__ b1, const float* __restrict__ dinv, ushort16* __restrict__ y1, int n){
  int node = blockIdx.x;
  if (node >= n) return;
  int f = threadIdx.x;
  float4 v = a1[node];
  float acc = v.x*W1[f] + v.y*W1[H+f] + v.z*W1[2*H+f] + b1[f];
  y1[(size_t)node*H + f] = f2bf(dinv[node] * fmaxf(acc, 0.f));
}

// a[d,:] = dinv[d] * sum_src y[src,:]   (bf16 gather 256B/row, fp32 accumulate)
// 16 nodes per 256-thread block; 16 lanes per node, 16B (8 bf16) per lane
__global__ __launch_bounds__(256) void k_agg128(const ushort16* __restrict__ y, const int* __restrict__ offsets,
      const int* __restrict__ csr_src, const float* __restrict__ dinv, float* __restrict__ a, int n){
  int node = blockIdx.x*16 + (threadIdx.x >> 4);
  if (node >= n) return;
  int f8 = (threadIdx.x & 15) * 8;
  int lo = offsets[node], hi = offsets[node+1];
  float a0=0,a1=0,a2=0,a3=0,a4=0,a5=0,a6=0,a7=0;
  #define ADDU(u) { a0+=bflo(u.x); a1+=bfhi(u.x); a2+=bflo(u.y); a3+=bfhi(u.y); \
                    a4+=bflo(u.z); a5+=bfhi(u.z); a6+=bflo(u.w); a7+=bfhi(u.w); }
  int e = lo;
  for (; e+4 <= hi; e += 4){
    int s0=csr_src[e], s1=csr_src[e+1], s2=csr_src[e+2], s3=csr_src[e+3];
    uint4 u0 = *(const uint4*)&y[(size_t)s0*H + f8];
    uint4 u1 = *(const uint4*)&y[(size_t)s1*H + f8];
    uint4 u2 = *(const uint4*)&y[(size_t)s2*H + f8];
    uint4 u3 = *(const uint4*)&y[(size_t)s3*H + f8];
    ADDU(u0); ADDU(u1); ADDU(u2); ADDU(u3);
  }
  for (; e < hi; e++){
    int s = csr_src[e];
    uint4 u = *(const uint4*)&y[(size_t)s*H + f8];
    ADDU(u);
  }
  #undef ADDU
  float dn = dinv[node];
  *(float4*)&a[(size_t)node*H + f8]     = make_float4(a0*dn, a1*dn, a2*dn, a3*dn);
  *(float4*)&a[(size_t)node*H + f8 + 4] = make_float4(a4*dn, a5*dn, a6*dn, a7*dn);
}

// dense 128x128: out = relu(a @ W + b); BF16OUT: y = bf16(dinv*out), else x = out (fp32)
// k-chunked so all LDS reads are b128
template<int BF16OUT>
__global__ __launch_bounds__(256) void k_dense128(const float* __restrict__ a, const float* __restrict__ W,
      const float* __restrict__ bias, const float* __restrict__ dinv,
      float* __restrict__ xout, ushort16* __restrict__ yout, int n){
  __shared__ float ws[64*H];   // 32KB: half of W
  __shared__ float xs[32*H];   // 16KB: 32 input rows
  int tid = threadIdx.x;
  int row0 = blockIdx.x * 32;
  for (int i = tid; i < 32*H/4; i += 256){
    int idx = i*4; int r = idx >> 7, c = idx & 127;
    int gr = row0 + r;
    float4 v = (gr < n) ? *(const float4*)&a[(size_t)gr*H + c] : make_float4(0,0,0,0);
    *(float4*)&xs[idx] = v;
  }
  int fb = (tid & 31) * 4;
  int rb = (tid >> 5) * 4;
  float acc[4][4] = {};
  for (int half = 0; half < 2; half++){
    __syncthreads();
    for (int i = tid; i < 64*H/4; i += 256){ int idx = i*4; *(float4*)&ws[idx] = *(const float4*)&W[half*64*H + idx]; }
    __syncthreads();
    for (int k = 0; k < 64; k += 4){
      float4 w0 = *(float4*)&ws[(k+0)*H + fb];
      float4 w1 = *(float4*)&ws[(k+1)*H + fb];
      float4 w2 = *(float4*)&ws[(k+2)*H + fb];
      float4 w3 = *(float4*)&ws[(k+3)*H + fb];
      #pragma unroll
      for (int j = 0; j < 4; j++){
        float4 xv = *(float4*)&xs[(rb+j)*H + half*64 + k];
        acc[j][0] += xv.x*w0.x + xv.y*w1.x + xv.z*w2.x + xv.w*w3.x;
        acc[j][1] += xv.x*w0.y + xv.y*w1.y + xv.z*w2.y + xv.w*w3.y;
        acc[j][2] += xv.x*w0.z + xv.y*w1.z + xv.z*w2.z + xv.w*w3.z;
        acc[j][3] += xv.x*w0.w + xv.y*w1.w + xv.z*w2.w + xv.w*w3.w;
      }
    }
  }
  float4 bv = *(const float4*)&bias[fb];
  for (int j = 0; j < 4; j++){
    int gr = row0 + rb + j;
    if (gr >= n) continue;
    float o0 = fmaxf(acc[j][0] + bv.x, 0.f);
    float o1 = fmaxf(acc[j][1] + bv.y, 0.f);
    float o2 = fmaxf(acc[j][2] + bv.z, 0.f);
    float o3 = fmaxf(acc[j][3] + bv.w, 0.f);
    if (BF16OUT){
      float dn = dinv[gr];
      ushort16 u0 = f2bf(o0*dn), u1 = f2bf(o1*dn), u2 = f2bf(o2*dn), u3 = f2bf(o3*dn);
      ushort16* p = &yout[(size_t)gr*H + fb];
      p[0]=u0; p[1]=u1; p[2]=u2; p[3]=u3;
    } else {
      *(float4*)&xout[(size_t)gr*H + fb] = make_float4(o0,o1,o2,o3);
    }
  }
}

// graph boundaries
__global__ __launch_bounds__(64) void k_bounds(const int* __restrict__ batch, int n, int G,
                                               int* __restrict__ gb){
  int g = blockIdx.x*blockDim.x + threadIdx.x;
  if (g > G) return;
  int lo = 0, hi = n;
  while (lo < hi){ int m = (lo + hi) >> 1; if (batch[m] < g) lo = m + 1; else hi = m; }
  gb[g] = lo;
}

// partial pooled sums
__global__ __launch_bounds__(128) void k_pool_partial(const float* __restrict__ x, const int* __restrict__ gb,
                                                      int S, float* __restrict__ gsum){
  int g = blockIdx.x, s = blockIdx.y;
  int lo = gb[g], hi = gb[g+1];
  int cnt = hi - lo;
  int a = lo + (int)(((long long)cnt * s) / S);
  int b = lo + (int)(((long long)cnt * (s+1)) / S);
  int f = threadIdx.x;
  float acc = 0.f;
  for (int i = a; i < b; i++) acc += x[(size_t)i*H + f];
  if (b > a) atomicAdd(&gsum[g*H + f], acc);
}

// MLP head
__global__ __launch_bounds__(64) void k_head(const float* __restrict__ gsum, const int* __restrict__ gb,
            const float* __restrict__ Wl1, const float* __restrict__ bl1,
            const float* __restrict__ Wl2, const float* __restrict__ bl2,
            float* __restrict__ out){
  int g = blockIdx.x;
  int t = threadIdx.x;
  __shared__ float gs[H];
  __shared__ float h1[64];
  float inv = 1.f / fmaxf((float)(gb[g+1] - gb[g]), 1.f);
  gs[t]      = gsum[g*H + t]      * inv;
  gs[64 + t] = gsum[g*H + 64 + t] * inv;
  __syncthreads();
  float acc = bl1[t];
  for (int k = 0; k < H; k++) acc += gs[k] * Wl1[k*64 + t];
  h1[t] = fmaxf(acc, 0.f);
  __syncthreads();
  if (t < 10){
    float o = bl2[t];
    for (int j = 0; j < 64; j++) o += h1[j] * Wl2[j*10 + t];
    out[g*10 + t] = o;
  }
}

extern "C" void kernel_launch(void* const* d_in, const int* in_sizes, int n_in,
                              void* d_out, int out_size, void* d_ws, size_t ws_size,
                              hipStream_t stream){
  const float* pos = (const float*)d_in[0];
  const int*  ei   = (const int*)d_in[1];
  const int*  batch= (const int*)d_in[2];
  const float* W1 = (const float*)d_in[3];
  const float* b1 = (const float*)d_in[4];
  const float* W2 = (const float*)d_in[5];
  const float* b2 = (const float*)d_in[6];
  const float* W3 = (const float*)d_in[7];
  const float* b3 = (const float*)d_in[8];
  const float* Wl1 = (const float*)d_in[9];
  const float* bl1 = (const float*)d_in[10];
  const float* Wl2 = (const float*)d_in[11];
  const float* bl2 = (const float*)d_in[12];
  float* out = (float*)d_out;

  int N = in_sizes[0] / 3;     // 50000
  int E = in_sizes[1] / 2;     // 800000
  int G = out_size / 10;       // 64
  const int S = 40;
  int B = (N + 1023) / 1024;   // <= 256

  // workspace carve (~57 MB)
  char* p = (char*)d_ws;
  auto carve = [&](size_t bytes)->char* { char* q = p; p += (bytes + 255) & ~(size_t)255; return q; };
  int*     deg     = (int*)    carve(sizeof(int)    * (size_t)N);
  int*     offsets = (int*)    carve(sizeof(int)    * (size_t)(N+1));
  int*     counter = (int*)    carve(sizeof(int)    * (size_t)N);
  float*   dinv    = (float*)  carve(sizeof(float)  * (size_t)N);
  int*     bsum    = (int*)    carve(sizeof(int)    * 256);
  int*     csr_src = (int*)    carve(sizeof(int)    * (size_t)(E+N));
  float4*  y0      = (float4*) carve(sizeof(float4) * (size_t)N);
  float4*  a1      = (float4*) carve(sizeof(float4) * (size_t)N);
  float*   bufA    = (float*)  carve(sizeof(float)  * (size_t)N * H);   // a2, a3
  char*    bufB    =           carve(sizeof(float)  * (size_t)N * H);   // y1/y2 (bf16), then x3 (fp32)
  int*     gb      = (int*)    carve(sizeof(int)    * (size_t)(G+1));
  float*   gsum    = (float*)  carve(sizeof(float)  * (size_t)G * H);

  ushort16* ybuf = (ushort16*)bufB;
  float*    x3   = (float*)bufB;

  const int* src = ei;
  const int* dst = ei + E;

  hipMemsetAsync(gsum, 0, sizeof(float)*(size_t)G*H, stream);
  hipLaunchKernelGGL(k_bounds, dim3((G+64)/64), dim3(64), 0, stream, batch, N, G, gb);

  hipLaunchKernelGGL(k_init,  dim3((N+255)/256),   dim3(256), 0, stream, deg, counter, N);
  hipLaunchKernelGGL(k_count, dim3((E+255)/256),   dim3(256), 0, stream, dst, E, deg);
  hipLaunchKernelGGL(k_scan1, dim3(B),             dim3(256), 0, stream, deg, N, offsets, bsum, dinv);
  hipLaunchKernelGGL(k_scan2, dim3(1),             dim3(256), 0, stream, bsum, B, N, offsets);
  hipLaunchKernelGGL(k_scan3, dim3(B),             dim3(256), 0, stream, offsets, N, bsum);
  hipLaunchKernelGGL(k_fill,  dim3((E+N+255)/256), dim3(256), 0, stream, src, dst, E, N, offsets, counter, csr_src);

  // layer 1 (aggregate-first: tiny 3-wide gather)
  hipLaunchKernelGGL(k_prescale, dim3((N+255)/256), dim3(256), 0, stream, pos, dinv, y0, N);
  hipLaunchKernelGGL(k_agg3,     dim3((N+255)/256), dim3(256), 0, stream, y0, offsets, csr_src, dinv, a1, N);
  hipLaunchKernelGGL(k_dense1,   dim3(N),           dim3(128), 0, stream, a1, W1, b1, dinv, ybuf, N);

  // layer 2
  hipLaunchKernelGGL(k_agg128,        dim3((N+15)/16), dim3(256), 0, stream, ybuf, offsets, csr_src, dinv, bufA, N);
  hipLaunchKernelGGL(k_dense128<1>,   dim3((N+31)/32), dim3(256), 0, stream, bufA, W2, b2, dinv, (float*)nullptr, ybuf, N);

  // layer 3
  hipLaunchKernelGGL(k_agg128,        dim3((N+15)/16), dim3(256), 0, stream, ybuf, offsets, csr_src, dinv, bufA, N);
  hipLaunchKernelGGL(k_dense128<0>,   dim3((N+31)/32), dim3(256), 0, stream, bufA, W3, b3, dinv, x3, (ushort16*)nullptr, N);

  hipLaunchKernelGGL(k_pool_partial, dim3(G, S), dim3(128), 0, stream, x3, gb, S, gsum);
  hipLaunchKernelGGL(k_head,         dim3(G),    dim3(64),  0, stream, gsum, gb, Wl1, bl1, Wl2, bl2, out);
}

// Round 6
// 284.619 us; speedup vs baseline: 3.0254x; 1.2283x over previous
//
#include <hip/hip_runtime.h>

#define H 128
typedef unsigned int uint32;
typedef unsigned short ushort16;
typedef __attribute__((ext_vector_type(8))) short bf16x8;
typedef __attribute__((ext_vector_type(4))) float f32x4;

static __device__ __forceinline__ ushort16 f2bf(float f){
  uint32 u = __float_as_uint(f);
  uint32 r = (u + 0x7fff + ((u >> 16) & 1)) >> 16;   // RNE bf16 (finite values)
  return (ushort16)r;
}
static __device__ __forceinline__ float bflo(uint32 u){ return __uint_as_float(u << 16); }
static __device__ __forceinline__ float bfhi(uint32 u){ return __uint_as_float(u & 0xffff0000u); }

// rank[e] = position of edge e within its dst bucket; deg counts real in-edges
__global__ __launch_bounds__(256) void k_count_rank(const int* __restrict__ dst, int E,
                                                    int* __restrict__ deg, int* __restrict__ rank){
  int i = blockIdx.x*256 + threadIdx.x;
  if (i < E) rank[i] = atomicAdd(&deg[dst[i]], 1);
}

// ---- multi-block exclusive scan of (deg+1) -> offsets, plus dinv = rsqrt(deg+1) ----
__global__ __launch_bounds__(256) void k_scan1(const int* __restrict__ deg, int n,
      int* __restrict__ offsets, int* __restrict__ bsum, float* __restrict__ dinv){
  __shared__ int sh[256];
  int b = blockIdx.x, t = threadIdx.x;
  int base = b*1024 + t*4;
  bool i0 = base+0 < n, i1 = base+1 < n, i2 = base+2 < n, i3 = base+3 < n;
  int d0=0,d1=0,d2=0,d3=0;
  if (i3){ int4 v = *(const int4*)&deg[base]; d0=v.x; d1=v.y; d2=v.z; d3=v.w; }
  else {
    if (i0) d0 = deg[base+0];
    if (i1) d1 = deg[base+1];
    if (i2) d2 = deg[base+2];
  }
  int e0 = i0? d0+1:0, e1 = i1? d1+1:0, e2 = i2? d2+1:0, e3 = i3? d3+1:0;   // +1 self-loop
  sh[t] = e0+e1+e2+e3;
  __syncthreads();
  for (int off=1; off<256; off<<=1){
    int v = sh[t];
    int add = (t>=off)? sh[t-off] : 0;
    __syncthreads();
    sh[t] = v+add;
    __syncthreads();
  }
  int o0 = (t==0)?0:sh[t-1];
  int o1 = o0+e0, o2 = o1+e1, o3 = o2+e2;
  if (i0){ offsets[base+0]=o0; dinv[base+0]=rsqrtf((float)(d0+1)); }
  if (i1){ offsets[base+1]=o1; dinv[base+1]=rsqrtf((float)(d1+1)); }
  if (i2){ offsets[base+2]=o2; dinv[base+2]=rsqrtf((float)(d2+1)); }
  if (i3){ offsets[base+3]=o3; dinv[base+3]=rsqrtf((float)(d3+1)); }
  if (t==255) bsum[b] = sh[255];
}

__global__ __launch_bounds__(256) void k_scan2(int* __restrict__ bsum, int B, int n, int* __restrict__ offsets){
  __shared__ int sh[256];
  int t = threadIdx.x;
  sh[t] = (t<B)? bsum[t] : 0;
  __syncthreads();
  for (int off=1; off<256; off<<=1){
    int v = sh[t];
    int add = (t>=off)? sh[t-off] : 0;
    __syncthreads();
    sh[t] = v+add;
    __syncthreads();
  }
  if (t<B) bsum[t] = (t==0)?0:sh[t-1];
  if (t==255) offsets[n] = sh[255];
}

__global__ __launch_bounds__(256) void k_scan3(int* __restrict__ offsets, int n, const int* __restrict__ bsum){
  int b = blockIdx.x, t = threadIdx.x;
  int add = bsum[b];
  int base = b*1024 + t*4;
  if (base+3 < n){
    int4 v = *(int4*)&offsets[base];
    v.x+=add; v.y+=add; v.z+=add; v.w+=add;
    *(int4*)&offsets[base] = v;
  } else {
    #pragma unroll
    for (int k=0;k<4;k++){ int i=base+k; if (i<n) offsets[i]+=add; }
  }
}

// atomic-free CSR fill: real edge e -> slot offsets[dst]+1+rank[e]; self-loop at slot offsets[i]
__global__ __launch_bounds__(256) void k_fill2(const int* __restrict__ src, const int* __restrict__ dst,
            int E, int n, const int* __restrict__ offsets, const int* __restrict__ rank,
            int* __restrict__ csr_src){
  int i = blockIdx.x*256 + threadIdx.x;
  if (i < E){
    csr_src[offsets[dst[i]] + 1 + rank[i]] = src[i];
  } else if (i < E + n){
    int j = i - E;
    csr_src[offsets[j]] = j;
  }
}

// y0[i] = dinv[i] * pos[i]  (padded float4)
__global__ __launch_bounds__(256) void k_prescale(const float* __restrict__ pos, const float* __restrict__ dinv,
                                                  float4* __restrict__ y0, int n){
  int i = blockIdx.x*256 + threadIdx.x;
  if (i < n){
    float d = dinv[i];
    y0[i] = make_float4(pos[3*i]*d, pos[3*i+1]*d, pos[3*i+2]*d, 0.f);
  }
}

// a1[d] = dinv[d] * sum_src y0[src]
__global__ __launch_bounds__(256) void k_agg3(const float4* __restrict__ y0, const int* __restrict__ offsets,
      const int* __restrict__ csr_src, const float* __restrict__ dinv, float4* __restrict__ a1, int n){
  int node = blockIdx.x*256 + threadIdx.x;
  if (node >= n) return;
  int lo = offsets[node], hi = offsets[node+1];
  float x=0.f, y=0.f, z=0.f;
  int e = lo;
  for (; e+2 <= hi; e += 2){
    int s0 = csr_src[e], s1 = csr_src[e+1];
    float4 v0 = y0[s0], v1 = y0[s1];
    x += v0.x + v1.x; y += v0.y + v1.y; z += v0.z + v1.z;
  }
  if (e < hi){ float4 v = y0[csr_src[e]]; x += v.x; y += v.y; z += v.z; }
  float dn = dinv[node];
  a1[node] = make_float4(x*dn, y*dn, z*dn, 0.f);
}

// y1[node,f] = bf16( dinv[node] * relu(a1[node] . W1[:,f] + b1[f]) )
__global__ __launch_bounds__(128) void k_dense1(const float4* __restrict__ a1, const float* __restrict__ W1,
      const float* __restrict__ b1, const float* __restrict__ dinv, ushort16* __restrict__ y1, int n){
  int node = blockIdx.x;
  if (node >= n) return;
  int f = threadIdx.x;
  float4 v = a1[node];
  float acc = v.x*W1[f] + v.y*W1[H+f] + v.z*W1[2*H+f] + b1[f];
  y1[(size_t)node*H + f] = f2bf(dinv[node] * fmaxf(acc, 0.f));
}

// a[d,:] = bf16( dinv[d] * sum_src y[src,:] )   (bf16 gather, fp32 accumulate, bf16 out)
// 16 nodes per 256-thread block; 16 lanes per node, 16B (8 bf16) per lane
__global__ __launch_bounds__(256) void k_agg128(const ushort16* __restrict__ y, const int* __restrict__ offsets,
      const int* __restrict__ csr_src, const float* __restrict__ dinv, ushort16* __restrict__ aout, int n){
  int node = blockIdx.x*16 + (threadIdx.x >> 4);
  if (node >= n) return;
  int f8 = (threadIdx.x & 15) * 8;
  int lo = offsets[node], hi = offsets[node+1];
  float a0=0,a1=0,a2=0,a3=0,a4=0,a5=0,a6=0,a7=0;
  #define ADDU(u) { a0+=bflo(u.x); a1+=bfhi(u.x); a2+=bflo(u.y); a3+=bfhi(u.y); \
                    a4+=bflo(u.z); a5+=bfhi(u.z); a6+=bflo(u.w); a7+=bfhi(u.w); }
  int e = lo;
  for (; e+4 <= hi; e += 4){
    int s0=csr_src[e], s1=csr_src[e+1], s2=csr_src[e+2], s3=csr_src[e+3];
    uint4 u0 = *(const uint4*)&y[(size_t)s0*H + f8];
    uint4 u1 = *(const uint4*)&y[(size_t)s1*H + f8];
    uint4 u2 = *(const uint4*)&y[(size_t)s2*H + f8];
    uint4 u3 = *(const uint4*)&y[(size_t)s3*H + f8];
    ADDU(u0); ADDU(u1); ADDU(u2); ADDU(u3);
  }
  for (; e < hi; e++){
    int s = csr_src[e];
    uint4 u = *(const uint4*)&y[(size_t)s*H + f8];
    ADDU(u);
  }
  #undef ADDU
  float dn = dinv[node];
  uint4 o;
  o.x = (uint32)f2bf(a0*dn) | ((uint32)f2bf(a1*dn) << 16);
  o.y = (uint32)f2bf(a2*dn) | ((uint32)f2bf(a3*dn) << 16);
  o.z = (uint32)f2bf(a4*dn) | ((uint32)f2bf(a5*dn) << 16);
  o.w = (uint32)f2bf(a6*dn) | ((uint32)f2bf(a7*dn) << 16);
  *(uint4*)&aout[(size_t)node*H + f8] = o;
}

// prep W (K=128 x N=128, row-major fp32) into MFMA B-fragment order, bf16:
// wp[((kt*8+ct)*64 + lane)*8 + j] = bf16( W[(kt*32 + (lane>>4)*8 + j)*128 + ct*16 + (lane&15)] )
__global__ __launch_bounds__(256) void k_wprep(const float* __restrict__ W, ushort16* __restrict__ wp){
  int tid = blockIdx.x*256 + threadIdx.x;   // 2048 threads total
  int frag = tid >> 6, lane = tid & 63;
  int kt = frag >> 3, ct = frag & 7;
  int m = lane & 15, quad = lane >> 4;
  const float* wrow = &W[(kt*32 + quad*8)*H + ct*16 + m];
  ushort16 vals[8];
  #pragma unroll
  for (int j = 0; j < 8; j++) vals[j] = f2bf(wrow[j*H]);
  uint4 o;
  o.x = (uint32)vals[0] | ((uint32)vals[1] << 16);
  o.y = (uint32)vals[2] | ((uint32)vals[3] << 16);
  o.z = (uint32)vals[4] | ((uint32)vals[5] << 16);
  o.w = (uint32)vals[6] | ((uint32)vals[7] << 16);
  *(uint4*)&wp[(size_t)tid*8] = o;
}

// MFMA dense: out = relu(a @ W + b); BF16OUT: y = bf16(dinv*out), else x = out (fp32)
// 64 rows/block, 4 waves x 16 rows, K=128 in 4 steps, 8 col-tiles of 16. No LDS.
template<int BF16OUT>
__global__ __launch_bounds__(256) void k_dense_mfma(const ushort16* __restrict__ a, const ushort16* __restrict__ wp,
      const float* __restrict__ bias, const float* __restrict__ dinv,
      float* __restrict__ xout, ushort16* __restrict__ yout, int n){
  int wave = threadIdx.x >> 6;
  int lane = threadIdx.x & 63;
  int m = lane & 15, quad = lane >> 4;
  int row0 = blockIdx.x*64 + wave*16;
  int arow = row0 + m;                 // A-operand row for this lane
  bool aok = arow < n;
  const bf16x8 az = {0,0,0,0,0,0,0,0};
  f32x4 acc[8];
  #pragma unroll
  for (int ct = 0; ct < 8; ct++){ f32x4 z = {0.f,0.f,0.f,0.f}; acc[ct] = z; }
  #pragma unroll
  for (int kt = 0; kt < 4; kt++){
    bf16x8 af = aok ? *(const bf16x8*)&a[(size_t)arow*H + kt*32 + quad*8] : az;
    #pragma unroll
    for (int ct = 0; ct < 8; ct++){
      bf16x8 bf = *(const bf16x8*)&wp[(size_t)((kt*8+ct)*64 + lane)*8];
      acc[ct] = __builtin_amdgcn_mfma_f32_16x16x32_bf16(af, bf, acc[ct], 0, 0, 0);
    }
  }
  // C/D layout: col = ct*16 + m, row (in tile) = quad*4 + r
  #pragma unroll
  for (int ct = 0; ct < 8; ct++){
    int col = ct*16 + m;
    float bv = bias[col];
    #pragma unroll
    for (int r = 0; r < 4; r++){
      int orow = row0 + quad*4 + r;
      if (orow < n){
        float v = fmaxf(acc[ct][r] + bv, 0.f);
        if (BF16OUT) yout[(size_t)orow*H + col] = f2bf(v * dinv[orow]);
        else         xout[(size_t)orow*H + col] = v;
      }
    }
  }
}

// graph boundaries
__global__ __launch_bounds__(64) void k_bounds(const int* __restrict__ batch, int n, int G,
                                               int* __restrict__ gb){
  int g = blockIdx.x*blockDim.x + threadIdx.x;
  if (g > G) return;
  int lo = 0, hi = n;
  while (lo < hi){ int m = (lo + hi) >> 1; if (batch[m] < g) lo = m + 1; else hi = m; }
  gb[g] = lo;
}

// partial pooled sums
__global__ __launch_bounds__(128) void k_pool_partial(const float* __restrict__ x, const int* __restrict__ gb,
                                                      int S, float* __restrict__ gsum){
  int g = blockIdx.x, s = blockIdx.y;
  int lo = gb[g], hi = gb[g+1];
  int cnt = hi - lo;
  int a = lo + (int)(((long long)cnt * s) / S);
  int b = lo + (int)(((long long)cnt * (s+1)) / S);
  int f = threadIdx.x;
  float acc = 0.f;
  for (int i = a; i < b; i++) acc += x[(size_t)i*H + f];
  if (b > a) atomicAdd(&gsum[g*H + f], acc);
}

// MLP head
__global__ __launch_bounds__(64) void k_head(const float* __restrict__ gsum, const int* __restrict__ gb,
            const float* __restrict__ Wl1, const float* __restrict__ bl1,
            const float* __restrict__ Wl2, const float* __restrict__ bl2,
            float* __restrict__ out){
  int g = blockIdx.x;
  int t = threadIdx.x;
  __shared__ float gs[H];
  __shared__ float h1[64];
  float inv = 1.f / fmaxf((float)(gb[g+1] - gb[g]), 1.f);
  gs[t]      = gsum[g*H + t]      * inv;
  gs[64 + t] = gsum[g*H + 64 + t] * inv;
  __syncthreads();
  float acc = bl1[t];
  for (int k = 0; k < H; k++) acc += gs[k] * Wl1[k*64 + t];
  h1[t] = fmaxf(acc, 0.f);
  __syncthreads();
  if (t < 10){
    float o = bl2[t];
    for (int j = 0; j < 64; j++) o += h1[j] * Wl2[j*10 + t];
    out[g*10 + t] = o;
  }
}

extern "C" void kernel_launch(void* const* d_in, const int* in_sizes, int n_in,
                              void* d_out, int out_size, void* d_ws, size_t ws_size,
                              hipStream_t stream){
  const float* pos = (const float*)d_in[0];
  const int*  ei   = (const int*)d_in[1];
  const int*  batch= (const int*)d_in[2];
  const float* W1 = (const float*)d_in[3];
  const float* b1 = (const float*)d_in[4];
  const float* W2 = (const float*)d_in[5];
  const float* b2 = (const float*)d_in[6];
  const float* W3 = (const float*)d_in[7];
  const float* b3 = (const float*)d_in[8];
  const float* Wl1 = (const float*)d_in[9];
  const float* bl1 = (const float*)d_in[10];
  const float* Wl2 = (const float*)d_in[11];
  const float* bl2 = (const float*)d_in[12];
  float* out = (float*)d_out;

  int N = in_sizes[0] / 3;     // 50000
  int E = in_sizes[1] / 2;     // 800000
  int G = out_size / 10;       // 64
  const int S = 40;
  int B = (N + 1023) / 1024;   // <= 256

  // workspace carve (~43 MB; x3 aliases the dead rank/y0/a1/ybuf region)
  char* p = (char*)d_ws;
  auto carve = [&](size_t bytes)->char* { char* q = p; p += (bytes + 255) & ~(size_t)255; return q; };
  int*      deg     = (int*)     carve(sizeof(int)    * (size_t)N);
  int*      offsets = (int*)     carve(sizeof(int)    * (size_t)(N+1));
  float*    dinv    = (float*)   carve(sizeof(float)  * (size_t)N);
  int*      bsum    = (int*)     carve(sizeof(int)    * 256);
  int*      gb      = (int*)     carve(sizeof(int)    * (size_t)(G+1));
  float*    gsum    = (float*)   carve(sizeof(float)  * (size_t)G * H);
  int*      csr_src = (int*)     carve(sizeof(int)    * (size_t)(E+N));
  ushort16* abuf    = (ushort16*)carve(sizeof(ushort16) * (size_t)N * H);   // a2/a3 bf16
  ushort16* wp2     = (ushort16*)carve(sizeof(ushort16) * 16384);
  ushort16* wp3     = (ushort16*)carve(sizeof(ushort16) * 16384);
  // big aliased region: early phase {rank, y0, a1, ybuf}; late phase {x3}
  size_t rank_b = (sizeof(int)    * (size_t)E        + 255) & ~(size_t)255;
  size_t y0_b   = (sizeof(float4) * (size_t)N        + 255) & ~(size_t)255;
  size_t a1_b   = (sizeof(float4) * (size_t)N        + 255) & ~(size_t)255;
  size_t ybuf_b = (sizeof(ushort16)* (size_t)N * H   + 255) & ~(size_t)255;
  size_t x3_b   = (sizeof(float)  * (size_t)N * H    + 255) & ~(size_t)255;
  size_t big_b  = rank_b + y0_b + a1_b + ybuf_b;
  if (x3_b > big_b) big_b = x3_b;
  char* big = carve(big_b);
  int*      rank = (int*)big;
  float4*   y0   = (float4*)(big + rank_b);
  float4*   a1   = (float4*)(big + rank_b + y0_b);
  ushort16* ybuf = (ushort16*)(big + rank_b + y0_b + a1_b);
  float*    x3   = (float*)big;   // written only after last ybuf read

  const int* src = ei;
  const int* dst = ei + E;

  hipMemsetAsync(deg, 0, sizeof(int)*(size_t)N, stream);
  hipMemsetAsync(gsum, 0, sizeof(float)*(size_t)G*H, stream);
  hipLaunchKernelGGL(k_bounds, dim3((G+64)/64), dim3(64), 0, stream, batch, N, G, gb);

  hipLaunchKernelGGL(k_count_rank, dim3((E+255)/256),   dim3(256), 0, stream, dst, E, deg, rank);
  hipLaunchKernelGGL(k_scan1,      dim3(B),             dim3(256), 0, stream, deg, N, offsets, bsum, dinv);
  hipLaunchKernelGGL(k_scan2,      dim3(1),             dim3(256), 0, stream, bsum, B, N, offsets);
  hipLaunchKernelGGL(k_scan3,      dim3(B),             dim3(256), 0, stream, offsets, N, bsum);
  hipLaunchKernelGGL(k_fill2,      dim3((E+N+255)/256), dim3(256), 0, stream, src, dst, E, N, offsets, rank, csr_src);

  hipLaunchKernelGGL(k_wprep, dim3(8), dim3(256), 0, stream, W2, wp2);
  hipLaunchKernelGGL(k_wprep, dim3(8), dim3(256), 0, stream, W3, wp3);

  // layer 1 (aggregate-first: tiny 3-wide gather)
  hipLaunchKernelGGL(k_prescale, dim3((N+255)/256), dim3(256), 0, stream, pos, dinv, y0, N);
  hipLaunchKernelGGL(k_agg3,     dim3((N+255)/256), dim3(256), 0, stream, y0, offsets, csr_src, dinv, a1, N);
  hipLaunchKernelGGL(k_dense1,   dim3(N),           dim3(128), 0, stream, a1, W1, b1, dinv, ybuf, N);

  // layer 2
  hipLaunchKernelGGL(k_agg128,        dim3((N+15)/16), dim3(256), 0, stream, ybuf, offsets, csr_src, dinv, abuf, N);
  hipLaunchKernelGGL(k_dense_mfma<1>, dim3((N+63)/64), dim3(256), 0, stream, abuf, wp2, b2, dinv, (float*)nullptr, ybuf, N);

  // layer 3
  hipLaunchKernelGGL(k_agg128,        dim3((N+15)/16), dim3(256), 0, stream, ybuf, offsets, csr_src, dinv, abuf, N);
  hipLaunchKernelGGL(k_dense_mfma<0>, dim3((N+63)/64), dim3(256), 0, stream, abuf, wp3, b3, dinv, x3, (ushort16*)nullptr, N);

  hipLaunchKernelGGL(k_pool_partial, dim3(G, S), dim3(128), 0, stream, x3, gb, S, gsum);
  hipLaunchKernelGGL(k_head,         dim3(G),    dim3(64),  0, stream, gsum, gb, Wl1, bl1, Wl2, bl2, out);
}